// Round 1
// baseline (1331.801 us; speedup 1.0000x reference)
//
#include <hip/hip_runtime.h>

#define BB 2048
#define UU 4096
#define SCAN_BLOCKS (BB / 256)   // 8 blocks, thread-per-row
#define EW_BLOCKS ((BB * (UU / 4)) / 256)  // 8192 blocks, float4 per thread

__global__ __launch_bounds__(256) void sdp_kernel(
    const float* __restrict__ dur,
    const float* __restrict__ speech,
    const float* __restrict__ residual_prev,
    const float* __restrict__ cached_prev,
    const int* __restrict__ unit_len,
    const int* __restrict__ sealed_len,
    const int* __restrict__ committed_prev,
    float* __restrict__ out)
{
    float* mat   = out;
    float* proj  = out + (size_t)BB * UU;
    float* resid = out + 2 * (size_t)BB * UU;
    float* cach  = out + 2 * (size_t)BB * UU + BB;
    float* comm  = out + 3 * (size_t)BB * UU + BB;

    int blk = blockIdx.x;
    if (blk < SCAN_BLOCKS) {
        // ---- serial scan over the active range [P, L) of one row per thread ----
        int b = blk * 256 + (int)threadIdx.x;
        int L = min(unit_len[b], sealed_len[b]);
        L = max(0, min(L, UU));
        int P = committed_prev[b];
        P = max(0, min(P, UU));
        float c = residual_prev[b];
        const size_t ro = (size_t)b * UU;
        for (int u = P; u < L; ++u) {
            float d = dur[ro + u];
            float m = (speech[ro + u] > 0.5f) ? 1.0f : 0.0f;
            float s = d + c;
            float t = fmaxf(s, 0.0f);          // total = max(0, dur + carry)
            float f = floorf(fmaxf(s, m));     // == sp ? max(1,floor(t)) : floor(t)
            c = t - f;                         // new carry (active units only)
            // commit_mask == 1 here, so all three outputs equal frames
            mat[ro + u]  = f;
            proj[ro + u] = f;
            cach[ro + u] = f;
        }
        resid[b] = c;
        comm[b] = (float)L;   // commit_mask.sum() == min(unit_len, sealed_len)
    } else {
        // ---- elementwise for everything outside [P, L) ----
        int i  = (blk - SCAN_BLOCKS) * 256 + (int)threadIdx.x; // float4 index
        int b  = i >> 10;           // UU/4 = 1024 float4 per row
        int u0 = (i & 1023) << 2;   // starting u of this float4
        int L = min(unit_len[b], sealed_len[b]);
        L = max(0, min(L, UU));
        int P = committed_prev[b];
        P = max(0, min(P, UU));
        size_t base = (size_t)b * UU + u0;

        float4 cp = make_float4(0.f, 0.f, 0.f, 0.f);
        if (u0 < P) cp = *reinterpret_cast<const float4*>(cached_prev + base);
        const float* cpf = reinterpret_cast<const float*>(&cp);

        float pv[4], mv[4];
        bool act[4];
        bool any = false;
        #pragma unroll
        for (int j = 0; j < 4; ++j) {
            int u = u0 + j;
            bool a = (u >= P) && (u < L);   // scan blocks own these elements
            act[j] = a;
            any |= a;
            float p = (u < P) ? cpf[j] : 0.0f;  // use_cache ? cached_prev : scanned(=0)
            pv[j] = p;
            mv[j] = (u < L) ? p : 0.0f;         // projected * commit_mask
        }
        if (!any) {
            *reinterpret_cast<float4*>(mat + base)  = make_float4(mv[0], mv[1], mv[2], mv[3]);
            *reinterpret_cast<float4*>(proj + base) = make_float4(pv[0], pv[1], pv[2], pv[3]);
            *reinterpret_cast<float4*>(cach + base) = make_float4(mv[0], mv[1], mv[2], mv[3]);
        } else {
            #pragma unroll
            for (int j = 0; j < 4; ++j) {
                if (!act[j]) {
                    mat[base + j]  = mv[j];
                    proj[base + j] = pv[j];
                    cach[base + j] = mv[j];
                }
            }
        }
    }
}

extern "C" void kernel_launch(void* const* d_in, const int* in_sizes, int n_in,
                              void* d_out, int out_size, void* d_ws, size_t ws_size,
                              hipStream_t stream) {
    const float* dur            = (const float*)d_in[0];
    const float* speech         = (const float*)d_in[1];
    const float* residual_prev  = (const float*)d_in[2];
    const float* cached_prev    = (const float*)d_in[3];
    const int*   unit_len       = (const int*)d_in[4];
    const int*   sealed_len     = (const int*)d_in[5];
    const int*   committed_prev = (const int*)d_in[6];

    int grid = SCAN_BLOCKS + EW_BLOCKS;  // 8 + 8192
    sdp_kernel<<<grid, 256, 0, stream>>>(dur, speech, residual_prev, cached_prev,
                                         unit_len, sealed_len, committed_prev,
                                         (float*)d_out);
}

// Round 2
// 342.564 us; speedup vs baseline: 3.8877x; 3.8877x over previous
//
#include <hip/hip_runtime.h>

#define BB 2048
#define UU 4096
#define SCAN_BLOCKS 8                      // 8 blocks x 256 threads = thread-per-row
#define EW_BLOCKS ((BB * (UU / 4)) / 256)  // 8192 blocks, float4 per thread
#define CH 32                              // scan chunk (elements); 8 x float4 per array

__global__ __launch_bounds__(256) void sdp_kernel(
    const float* __restrict__ dur,
    const float* __restrict__ speech,
    const float* __restrict__ residual_prev,
    const float* __restrict__ cached_prev,
    const int* __restrict__ unit_len,
    const int* __restrict__ sealed_len,
    const int* __restrict__ committed_prev,
    float* __restrict__ out)
{
    float* mat   = out;
    float* proj  = out + (size_t)BB * UU;
    float* resid = out + 2 * (size_t)BB * UU;
    float* cach  = out + 2 * (size_t)BB * UU + BB;
    float* comm  = out + 3 * (size_t)BB * UU + BB;

    int blk = blockIdx.x;
    if (blk < SCAN_BLOCKS) {
        // ---- software-pipelined serial scan over [P, L) of one row per thread ----
        int b = blk * 256 + (int)threadIdx.x;
        int L = min(unit_len[b], sealed_len[b]);
        L = max(0, min(L, UU));
        int P = committed_prev[b];
        P = max(0, min(P, UU));
        float c = residual_prev[b];
        const size_t ro = (size_t)b * UU;

        if (P < L) {
            int base0 = P & ~(CH - 1);
            int nch = (L - base0 + CH - 1) / CH;   // chunk end never exceeds UU (4096%32==0)
            const float4* dp  = reinterpret_cast<const float4*>(dur + ro);
            const float4* spp = reinterpret_cast<const float4*>(speech + ro);

            float4 dA[CH / 4], sA[CH / 4];
            int q0 = base0 >> 2;
            #pragma unroll
            for (int j = 0; j < CH / 4; ++j) { dA[j] = dp[q0 + j]; sA[j] = spp[q0 + j]; }

            for (int ci = 0; ci < nch; ++ci) {
                int base = base0 + ci * CH;
                float4 dB[CH / 4], sB[CH / 4];
                bool has_next = (ci + 1 < nch);
                if (has_next) {
                    int q = (base + CH) >> 2;
                    #pragma unroll
                    for (int j = 0; j < CH / 4; ++j) { dB[j] = dp[q + j]; sB[j] = spp[q + j]; }
                }
                const float* dd = reinterpret_cast<const float*>(dA);
                const float* ss = reinterpret_cast<const float*>(sA);

                #pragma unroll
                for (int g = 0; g < CH / 4; ++g) {
                    float fv[4];
                    #pragma unroll
                    for (int j = 0; j < 4; ++j) {
                        int u = base + g * 4 + j;
                        float d = dd[g * 4 + j];
                        float m = (ss[g * 4 + j] > 0.5f) ? 1.0f : 0.0f;
                        float s = d + c;
                        float t = fmaxf(s, 0.0f);           // total
                        float fr = floorf(fmaxf(s, m));     // frames (speech forces >=1)
                        if ((u >= P) & (u < L)) c = t - fr; // carry only on active units
                        fv[j] = fr;
                    }
                    int u0 = base + g * 4;
                    if (u0 >= P && u0 + 4 <= L) {           // fully active group: float4 stores
                        float4 v = make_float4(fv[0], fv[1], fv[2], fv[3]);
                        *reinterpret_cast<float4*>(mat  + ro + u0) = v;
                        *reinterpret_cast<float4*>(proj + ro + u0) = v;
                        *reinterpret_cast<float4*>(cach + ro + u0) = v;
                    } else if (u0 < L && u0 + 4 > P) {      // boundary group: scalar predicated
                        #pragma unroll
                        for (int j = 0; j < 4; ++j) {
                            int u = u0 + j;
                            if (u >= P && u < L) {
                                mat[ro + u]  = fv[j];
                                proj[ro + u] = fv[j];
                                cach[ro + u] = fv[j];
                            }
                        }
                    }
                }
                if (has_next) {
                    #pragma unroll
                    for (int j = 0; j < CH / 4; ++j) { dA[j] = dB[j]; sA[j] = sB[j]; }
                }
            }
        }
        resid[b] = c;
        comm[b] = (float)L;   // commit_mask.sum() == clipped min(unit_len, sealed_len)
    } else {
        // ---- elementwise for everything outside [P, L) ----
        int i  = (blk - SCAN_BLOCKS) * 256 + (int)threadIdx.x; // float4 index
        int b  = i >> 10;           // UU/4 = 1024 float4 per row
        int u0 = (i & 1023) << 2;   // starting u of this float4
        int L = min(unit_len[b], sealed_len[b]);
        L = max(0, min(L, UU));
        int P = committed_prev[b];
        P = max(0, min(P, UU));
        size_t base = (size_t)b * UU + u0;

        float4 cp = make_float4(0.f, 0.f, 0.f, 0.f);
        if (u0 < P) cp = *reinterpret_cast<const float4*>(cached_prev + base);
        const float* cpf = reinterpret_cast<const float*>(&cp);

        float pv[4], mv[4];
        bool act[4];
        bool any = false;
        #pragma unroll
        for (int j = 0; j < 4; ++j) {
            int u = u0 + j;
            bool a = (u >= P) && (u < L);   // scan threads own these elements
            act[j] = a;
            any |= a;
            float p = (u < P) ? cpf[j] : 0.0f;  // use_cache ? cached_prev : scanned(=0)
            pv[j] = p;
            mv[j] = (u < L) ? p : 0.0f;         // projected * commit_mask
        }
        if (!any) {
            *reinterpret_cast<float4*>(mat + base)  = make_float4(mv[0], mv[1], mv[2], mv[3]);
            *reinterpret_cast<float4*>(proj + base) = make_float4(pv[0], pv[1], pv[2], pv[3]);
            *reinterpret_cast<float4*>(cach + base) = make_float4(mv[0], mv[1], mv[2], mv[3]);
        } else {
            #pragma unroll
            for (int j = 0; j < 4; ++j) {
                if (!act[j]) {
                    mat[base + j]  = mv[j];
                    proj[base + j] = pv[j];
                    cach[base + j] = mv[j];
                }
            }
        }
    }
}

extern "C" void kernel_launch(void* const* d_in, const int* in_sizes, int n_in,
                              void* d_out, int out_size, void* d_ws, size_t ws_size,
                              hipStream_t stream) {
    const float* dur            = (const float*)d_in[0];
    const float* speech         = (const float*)d_in[1];
    const float* residual_prev  = (const float*)d_in[2];
    const float* cached_prev    = (const float*)d_in[3];
    const int*   unit_len       = (const int*)d_in[4];
    const int*   sealed_len     = (const int*)d_in[5];
    const int*   committed_prev = (const int*)d_in[6];

    int grid = SCAN_BLOCKS + EW_BLOCKS;  // 8 + 8192
    sdp_kernel<<<grid, 256, 0, stream>>>(dur, speech, residual_prev, cached_prev,
                                         unit_len, sealed_len, committed_prev,
                                         (float*)d_out);
}

// Round 3
// 337.423 us; speedup vs baseline: 3.9470x; 1.0152x over previous
//
#include <hip/hip_runtime.h>

#define BB 2048
#define UU 4096
#define CH 32                 // elements per chunk
#define NGR 8                 // 4-element groups per chunk
#define DEP 4                 // LDS pipeline slots
#define SCAN_GRID 32          // 32 blocks x 64 threads = thread-per-row
#define EW_GRID ((BB * (UU / 4)) / 256)

typedef __attribute__((address_space(3))) void lds_void;
typedef __attribute__((address_space(1))) const void gbl_void;

__device__ __forceinline__ void gl_lds16(const float* g, float* l) {
    // async global->LDS, 16B/lane; dest = uniform base + lane*16
    __builtin_amdgcn_global_load_lds((gbl_void*)g, (lds_void*)l, 16, 0, 0);
}

__global__ __launch_bounds__(64) void scan_kernel(
    const float* __restrict__ dur,
    const float* __restrict__ speech,
    const float* __restrict__ residual_prev,
    const float* __restrict__ cached_prev,
    const int* __restrict__ unit_len,
    const int* __restrict__ sealed_len,
    const int* __restrict__ committed_prev,
    float* __restrict__ out)
{
    float* mat   = out;
    float* proj  = out + (size_t)BB * UU;
    float* resid = out + 2 * (size_t)BB * UU;
    float* cach  = resid + BB;
    float* comm  = cach + (size_t)BB * UU;

    __shared__ float buf[DEP][2][NGR][256];   // [slot][arr][group][lane*4+j] = 64KB

    const int lane = (int)threadIdx.x;
    const int b = blockIdx.x * 64 + lane;
    int L = min(unit_len[b], sealed_len[b]); L = max(0, min(L, UU));
    int P = committed_prev[b];               P = max(0, min(P, UU));
    float c = residual_prev[b];
    const size_t ro = (size_t)b * UU;
    const int gs = P >> 2, ge = (L + 3) >> 2;
    const bool own = (P < L);

    // cached values for the partial group at the P boundary (group gs)
    float cb[4] = {0.f, 0.f, 0.f, 0.f};
    if (own && (P & 3)) {
        float4 t = *reinterpret_cast<const float4*>(cached_prev + ro + (size_t)(gs << 2));
        cb[0] = t.x; cb[1] = t.y; cb[2] = t.z; cb[3] = t.w;
    }

    // wave-uniform trip count
    int kmax = own ? ((L + CH - 1) >> 5) : 0;
    #pragma unroll
    for (int d = 1; d < 64; d <<= 1) kmax = max(kmax, __shfl_xor(kmax, d));

    if (kmax > 0) {
        const float* dp = dur + ro;
        const float* sp = speech + ro;
        // prologue: fill slots 0..DEP-2
        for (int k = 0; k < DEP - 1; ++k) {
            int kk = min(k, kmax - 1);
            #pragma unroll
            for (int g = 0; g < NGR; ++g) {
                gl_lds16(dp + kk * CH + g * 4, &buf[k][0][g][0]);
                gl_lds16(sp + kk * CH + g * 4, &buf[k][1][g][0]);
            }
        }
        for (int i = 0; i < kmax; ++i) {
            // issue prefetch for chunk i+DEP-1 (clamped; keeps vmcnt accounting uniform)
            int pre = i + DEP - 1;
            int kk = min(pre, kmax - 1);
            int ps = pre & (DEP - 1);
            #pragma unroll
            for (int g = 0; g < NGR; ++g) {
                gl_lds16(dp + kk * CH + g * 4, &buf[ps][0][g][0]);
                gl_lds16(sp + kk * CH + g * 4, &buf[ps][1][g][0]);
            }
            // 48 loads (3 chunks) were issued after chunk i's 16 loads -> vmcnt(48)
            // guarantees chunk i's DMA landed. Stores issued in between only
            // strengthen the wait (in-order vmcnt retirement).
            asm volatile("s_waitcnt vmcnt(48)" ::: "memory");
            const int s = i & (DEP - 1);
            #pragma unroll
            for (int g = 0; g < NGR; ++g) {
                float4 dv = *reinterpret_cast<const float4*>(&buf[s][0][g][lane << 2]);
                float4 sv = *reinterpret_cast<const float4*>(&buf[s][1][g][lane << 2]);
                const int u0 = i * CH + g * 4;
                float dd[4] = {dv.x, dv.y, dv.z, dv.w};
                float sm[4] = {sv.x, sv.y, sv.z, sv.w};
                float fv[4];
                #pragma unroll
                for (int j = 0; j < 4; ++j) {
                    const int u = u0 + j;
                    float m  = (sm[j] > 0.5f) ? 1.0f : 0.0f;
                    float sf = dd[j] + c;
                    float t  = fmaxf(sf, 0.f);
                    float fr = floorf(fmaxf(sf, m));
                    if ((u >= P) && (u < L)) c = t - fr;     // carry on active only
                    fv[j] = (u < P) ? cb[j] : ((u < L) ? fr : 0.f);
                }
                const int gg = u0 >> 2;
                if (own && gg >= gs && gg < ge) {            // scan-owned group
                    float4 v4 = make_float4(fv[0], fv[1], fv[2], fv[3]);
                    *reinterpret_cast<float4*>(mat  + ro + u0) = v4;
                    *reinterpret_cast<float4*>(proj + ro + u0) = v4;
                    *reinterpret_cast<float4*>(cach + ro + u0) = v4;
                }
            }
        }
    }
    resid[b] = c;
    comm[b]  = (float)L;
}

__global__ __launch_bounds__(256) void ew_kernel(
    const float* __restrict__ cached_prev,
    const int* __restrict__ unit_len,
    const int* __restrict__ sealed_len,
    const int* __restrict__ committed_prev,
    float* __restrict__ out)
{
    float* mat   = out;
    float* proj  = out + (size_t)BB * UU;
    float* resid = out + 2 * (size_t)BB * UU;
    float* cach  = resid + BB;

    int i  = blockIdx.x * 256 + (int)threadIdx.x;  // float4 (= group) index
    int b  = i >> 10;
    int q  = i & 1023;                              // group index within row
    int u0 = q << 2;
    int L = min(unit_len[b], sealed_len[b]); L = max(0, min(L, UU));
    int P = committed_prev[b];               P = max(0, min(P, UU));
    const int gs = P >> 2, ge = (L + 3) >> 2;
    if ((P < L) && (q >= gs) && (q < ge)) return;   // scan kernel owns this group

    size_t base = (size_t)b * UU + u0;
    float4 cp4 = make_float4(0.f, 0.f, 0.f, 0.f);
    if (u0 < P) cp4 = *reinterpret_cast<const float4*>(cached_prev + base);
    const float* cpf = reinterpret_cast<const float*>(&cp4);

    float pv[4], mv[4];
    #pragma unroll
    for (int j = 0; j < 4; ++j) {
        int u = u0 + j;
        pv[j] = (u < P) ? cpf[j] : 0.0f;            // no active elems in ew-owned groups
        mv[j] = (u < L) ? pv[j] : 0.0f;
    }
    *reinterpret_cast<float4*>(mat  + base) = make_float4(mv[0], mv[1], mv[2], mv[3]);
    *reinterpret_cast<float4*>(proj + base) = make_float4(pv[0], pv[1], pv[2], pv[3]);
    *reinterpret_cast<float4*>(cach + base) = make_float4(mv[0], mv[1], mv[2], mv[3]);
}

extern "C" void kernel_launch(void* const* d_in, const int* in_sizes, int n_in,
                              void* d_out, int out_size, void* d_ws, size_t ws_size,
                              hipStream_t stream) {
    const float* dur            = (const float*)d_in[0];
    const float* speech         = (const float*)d_in[1];
    const float* residual_prev  = (const float*)d_in[2];
    const float* cached_prev    = (const float*)d_in[3];
    const int*   unit_len       = (const int*)d_in[4];
    const int*   sealed_len     = (const int*)d_in[5];
    const int*   committed_prev = (const int*)d_in[6];

    scan_kernel<<<SCAN_GRID, 64, 0, stream>>>(dur, speech, residual_prev, cached_prev,
                                              unit_len, sealed_len, committed_prev,
                                              (float*)d_out);
    ew_kernel<<<EW_GRID, 256, 0, stream>>>(cached_prev, unit_len, sealed_len,
                                           committed_prev, (float*)d_out);
}

// Round 4
// 259.987 us; speedup vs baseline: 5.1226x; 1.2978x over previous
//
#include <hip/hip_runtime.h>

#define BB 2048
#define UU 4096
#define TC 64                  // tile columns
#define SCAN_GRID 32           // 32 blocks x 64 threads, lane = row
#define EW_GRID ((BB * (UU / 4)) / 256)

typedef __attribute__((address_space(3))) void lds_void;
typedef __attribute__((address_space(1))) const void gbl_void;

__device__ __forceinline__ void gl_lds16(const float* g, float* l) {
    // async global->LDS DMA: dest = uniform base + lane*16, source per-lane
    __builtin_amdgcn_global_load_lds((gbl_void*)g, (lds_void*)l, 16, 0, 0);
}

// stage one 64x64 tile of dur+speech into swizzled LDS buffers.
// LDS layout: float4-slot s = row*16 + (g ^ (row&7)); staged by pre-swizzling
// the GLOBAL source f4-index (gl_lds dest is linear).
__device__ __forceinline__ void stage_tile(const float* __restrict__ dur,
                                           const float* __restrict__ spe,
                                           float* dst0, float* dst1,
                                           int brow, int c0, int lane) {
    #pragma unroll
    for (int it = 0; it < 16; ++it) {
        int row = it * 4 + (lane >> 4);
        int gsw = (lane & 15) ^ (row & 7);
        size_t off = (size_t)(brow + row) * UU + (size_t)(c0 + gsw * 4);
        gl_lds16(dur + off, dst0 + it * 256);
        gl_lds16(spe + off, dst1 + it * 256);
    }
}

__global__ __launch_bounds__(64) void scan_kernel(
    const float* __restrict__ dur,
    const float* __restrict__ speech,
    const float* __restrict__ residual_prev,
    const float* __restrict__ cached_prev,
    const int* __restrict__ unit_len,
    const int* __restrict__ sealed_len,
    const int* __restrict__ committed_prev,
    float* __restrict__ out)
{
    float* mat   = out;
    float* proj  = out + (size_t)BB * UU;
    float* resid = out + 2 * (size_t)BB * UU;
    float* cach  = resid + BB;
    float* comm  = cach + (size_t)BB * UU;

    __shared__ __align__(16) float lin[2][2][64 * TC];  // [buf][arr][slot*4] 64KB
    __shared__ __align__(16) float lout[64 * TC];       // 16KB
    __shared__ int lgs[64], lge[64];

    const int l = (int)threadIdx.x;
    const int brow = blockIdx.x * 64;
    const int b = brow + l;
    int L = min(unit_len[b], sealed_len[b]); L = max(0, min(L, UU));
    int P = committed_prev[b];               P = max(0, min(P, UU));
    float c = residual_prev[b];
    const size_t ro = (size_t)b * UU;
    const int gs = P >> 2, ge = (L + 3) >> 2;
    const bool own = (P < L);
    lgs[l] = own ? gs : 0x7fffffff;
    lge[l] = own ? ge : 0;

    float cb[4] = {0.f, 0.f, 0.f, 0.f};
    if (own && (P & 3)) {
        float4 t = *reinterpret_cast<const float4*>(cached_prev + ro + (size_t)(gs << 2));
        cb[0] = t.x; cb[1] = t.y; cb[2] = t.z; cb[3] = t.w;
    }

    // block-uniform tile range
    int alo = own ? (gs >> 4) : 0x7fffffff;
    int ahi = own ? ((ge + 15) >> 4) : 0;
    #pragma unroll
    for (int d = 1; d < 64; d <<= 1) {
        alo = min(alo, __shfl_xor(alo, d));
        ahi = max(ahi, __shfl_xor(ahi, d));
    }

    // hoisted sweep ownership params (row = it*4 + (l>>4), fixed per lane)
    int sgsv[16], sgev[16];
    #pragma unroll
    for (int it = 0; it < 16; ++it) {
        int r = it * 4 + (l >> 4);
        sgsv[it] = lgs[r];
        sgev[it] = lge[r];
    }

    if (alo < ahi) {
        stage_tile(dur, speech, &lin[alo & 1][0][0], &lin[alo & 1][1][0], brow, alo * TC, l);
        asm volatile("s_waitcnt vmcnt(0)" ::: "memory");

        for (int tt = alo; tt < ahi; ++tt) {
            const int bb = tt & 1;
            if (tt + 1 < ahi) {
                stage_tile(dur, speech, &lin[bb ^ 1][0][0], &lin[bb ^ 1][1][0],
                           brow, (tt + 1) * TC, l);
                // in-order completion: all but the newest 48 ops (next loads
                // + freshest stores) retired => this tile's 32 loads landed.
                asm volatile("s_waitcnt vmcnt(48)" ::: "memory");
            } else {
                asm volatile("s_waitcnt vmcnt(0)" ::: "memory");
            }

            const int c0 = tt * TC;
            // serial carry chain over this tile's 64 columns (lane = row)
            #pragma unroll
            for (int g = 0; g < 16; ++g) {
                const int slot = l * 16 + (g ^ (l & 7));
                float4 dv = *reinterpret_cast<const float4*>(&lin[bb][0][slot * 4]);
                float4 sv = *reinterpret_cast<const float4*>(&lin[bb][1][slot * 4]);
                float dd[4] = {dv.x, dv.y, dv.z, dv.w};
                float sm[4] = {sv.x, sv.y, sv.z, sv.w};
                float fv[4];
                #pragma unroll
                for (int j = 0; j < 4; ++j) {
                    const int u = c0 + g * 4 + j;
                    float m  = (sm[j] > 0.5f) ? 1.0f : 0.0f;
                    float s  = dd[j] + c;
                    float t  = fmaxf(s, 0.f);
                    float fr = floorf(fmaxf(s, m));
                    bool act = (u >= P) & (u < L);
                    c = act ? (t - fr) : c;
                    fv[j] = (u < P) ? cb[j] : ((u < L) ? fr : 0.f);
                }
                *reinterpret_cast<float4*>(&lout[slot * 4]) =
                    make_float4(fv[0], fv[1], fv[2], fv[3]);
            }

            // coalesced store sweep: lane -> (row = it*4 + l>>4, cg = l&15)
            const int cg = l & 15;
            #pragma unroll
            for (int it = 0; it < 16; ++it) {
                int row = it * 4 + (l >> 4);
                int slot = row * 16 + (cg ^ (row & 7));
                float4 v = *reinterpret_cast<const float4*>(&lout[slot * 4]);
                int gg = tt * 16 + cg;
                if ((gg >= sgsv[it]) & (gg < sgev[it])) {
                    size_t o = (size_t)(brow + row) * UU + (size_t)(c0 + cg * 4);
                    *reinterpret_cast<float4*>(mat  + o) = v;
                    *reinterpret_cast<float4*>(proj + o) = v;
                    *reinterpret_cast<float4*>(cach + o) = v;
                }
            }
            // pin store issue before next iteration's stage (keeps vmcnt math valid)
            asm volatile("" ::: "memory");
        }
    }
    resid[b] = c;
    comm[b]  = (float)L;
}

__global__ __launch_bounds__(256) void ew_kernel(
    const float* __restrict__ cached_prev,
    const int* __restrict__ unit_len,
    const int* __restrict__ sealed_len,
    const int* __restrict__ committed_prev,
    float* __restrict__ out)
{
    float* mat   = out;
    float* proj  = out + (size_t)BB * UU;
    float* resid = out + 2 * (size_t)BB * UU;
    float* cach  = resid + BB;

    int i  = blockIdx.x * 256 + (int)threadIdx.x;  // float4 (= group) index
    int b  = i >> 10;
    int q  = i & 1023;
    int u0 = q << 2;
    int L = min(unit_len[b], sealed_len[b]); L = max(0, min(L, UU));
    int P = committed_prev[b];               P = max(0, min(P, UU));
    const int gs = P >> 2, ge = (L + 3) >> 2;
    if ((P < L) && (q >= gs) && (q < ge)) return;   // scan kernel owns this group

    size_t base = (size_t)b * UU + u0;
    float4 cp4 = make_float4(0.f, 0.f, 0.f, 0.f);
    if (u0 < P) cp4 = *reinterpret_cast<const float4*>(cached_prev + base);
    const float* cpf = reinterpret_cast<const float*>(&cp4);

    float pv[4], mv[4];
    #pragma unroll
    for (int j = 0; j < 4; ++j) {
        int u = u0 + j;
        pv[j] = (u < P) ? cpf[j] : 0.0f;
        mv[j] = (u < L) ? pv[j] : 0.0f;
    }
    *reinterpret_cast<float4*>(mat  + base) = make_float4(mv[0], mv[1], mv[2], mv[3]);
    *reinterpret_cast<float4*>(proj + base) = make_float4(pv[0], pv[1], pv[2], pv[3]);
    *reinterpret_cast<float4*>(cach + base) = make_float4(mv[0], mv[1], mv[2], mv[3]);
}

extern "C" void kernel_launch(void* const* d_in, const int* in_sizes, int n_in,
                              void* d_out, int out_size, void* d_ws, size_t ws_size,
                              hipStream_t stream) {
    const float* dur            = (const float*)d_in[0];
    const float* speech         = (const float*)d_in[1];
    const float* residual_prev  = (const float*)d_in[2];
    const float* cached_prev    = (const float*)d_in[3];
    const int*   unit_len       = (const int*)d_in[4];
    const int*   sealed_len     = (const int*)d_in[5];
    const int*   committed_prev = (const int*)d_in[6];

    scan_kernel<<<SCAN_GRID, 64, 0, stream>>>(dur, speech, residual_prev, cached_prev,
                                              unit_len, sealed_len, committed_prev,
                                              (float*)d_out);
    ew_kernel<<<EW_GRID, 256, 0, stream>>>(cached_prev, unit_len, sealed_len,
                                           committed_prev, (float*)d_out);
}

// Round 5
// 156.897 us; speedup vs baseline: 8.4884x; 1.6571x over previous
//
#include <hip/hip_runtime.h>

#define BB 2048
#define UU 4096
#define TC 64
#define NSCAN 32

typedef __attribute__((address_space(3))) void lds_void;
typedef __attribute__((address_space(1))) const void gbl_void;

__device__ __forceinline__ void gl_lds16(const float* g, float* l) {
    // async global->LDS DMA: dest = uniform base + lane*16, source per-lane
    __builtin_amdgcn_global_load_lds((gbl_void*)g, (lds_void*)l, 16, 0, 0);
}

#if __has_builtin(__builtin_amdgcn_fractf)
#define FRACTF(x) __builtin_amdgcn_fractf(x)
#else
#define FRACTF(x) ((x) - floorf(x))
#endif

// stage one 64x64 tile into swizzled LDS: slot = row*16 + (g ^ (row&7)),
// achieved by pre-swizzling the GLOBAL source (gl_lds dest is linear).
__device__ __forceinline__ void stage_tile(const float* __restrict__ src,
                                           float* dstbase, int brow, int c0, int l) {
    #pragma unroll
    for (int it = 0; it < 16; ++it) {
        int row = (it << 2) + (l >> 4);
        int gsw = (l & 15) ^ (row & 7);
        const float* g = src + (size_t)(brow + row) * UU + (size_t)(c0 + (gsw << 2));
        gl_lds16(g, dstbase + it * 256);
    }
}

__global__ __launch_bounds__(256) void fused_kernel(
    const float* __restrict__ dur,
    const float* __restrict__ speech,
    const float* __restrict__ residual_prev,
    const float* __restrict__ cached_prev,
    const int* __restrict__ unit_len,
    const int* __restrict__ sealed_len,
    const int* __restrict__ committed_prev,
    float* __restrict__ out)
{
    float* mat   = out;
    float* proj  = out + (size_t)BB * UU;
    float* resid = out + 2 * (size_t)BB * UU;
    float* cach  = resid + BB;
    float* comm  = cach + (size_t)BB * UU;

    const int tid = (int)threadIdx.x;

    if (blockIdx.x >= NSCAN) {
        // ---------------- elementwise path: one row per block ----------------
        int r = (int)blockIdx.x - NSCAN;
        int L = min(unit_len[r], sealed_len[r]); L = max(0, min(L, UU));
        int P = committed_prev[r];               P = max(0, min(P, UU));
        int gs = P >> 2, ge = (L + 3) >> 2;
        bool own = P < L;
        size_t base = (size_t)r * UU;
        #pragma unroll
        for (int k2 = 0; k2 < 4; ++k2) {
            int g = (k2 << 8) + tid;                 // group index, coalesced
            if (own && g >= gs && g < ge) continue;  // scan path owns these
            int u0 = g << 2;
            float4 pv = make_float4(0.f, 0.f, 0.f, 0.f);
            if (u0 < P) pv = *reinterpret_cast<const float4*>(cached_prev + base + u0);
            float4 p4, m4;
            p4.x = (u0 + 0 < P) ? pv.x : 0.f;
            p4.y = (u0 + 1 < P) ? pv.y : 0.f;
            p4.z = (u0 + 2 < P) ? pv.z : 0.f;
            p4.w = (u0 + 3 < P) ? pv.w : 0.f;
            m4.x = (u0 + 0 < L) ? p4.x : 0.f;
            m4.y = (u0 + 1 < L) ? p4.y : 0.f;
            m4.z = (u0 + 2 < L) ? p4.z : 0.f;
            m4.w = (u0 + 3 < L) ? p4.w : 0.f;
            *reinterpret_cast<float4*>(mat  + base + u0) = m4;
            *reinterpret_cast<float4*>(proj + base + u0) = p4;
            *reinterpret_cast<float4*>(cach + base + u0) = m4;
        }
        return;
    }

    // ---------------- scan path: 4 waves, producer/consumer ----------------
    __shared__ __align__(16) float lin[3][2][64 * TC];   // 96 KB staging ring
    __shared__ __align__(16) float lout[2][64 * TC];     // 32 KB result ring
    __shared__ __align__(16) float lcb[64][4];
    __shared__ int lP[64], lL[64];
    __shared__ int uni2[2];

    const int w = tid >> 6;
    const int l = tid & 63;
    const int brow = (int)blockIdx.x << 6;

    float creg = 0.f;
    int Pl = 0, Lr_ = 0;
    unsigned kspanU = 0;

    if (w == 0) {
        int b = brow + l;
        int Lr = min(unit_len[b], sealed_len[b]); Lr = max(0, min(Lr, UU));
        int Pr = committed_prev[b];               Pr = max(0, min(Pr, UU));
        creg = residual_prev[b];
        lP[l] = Pr; lL[l] = Lr;
        Pl = Pr; Lr_ = Lr;
        bool own = Pr < Lr;
        kspanU = own ? (unsigned)(Lr - Pr) : 0u;
        float4 cbv = make_float4(0.f, 0.f, 0.f, 0.f);
        if (own && (Pr & 3))
            cbv = *reinterpret_cast<const float4*>(cached_prev + (size_t)b * UU + (size_t)(Pr & ~3));
        *reinterpret_cast<float4*>(&lcb[l][0]) = cbv;
        int a = own ? (Pr >> 6) : 0x7fffffff;
        int h = own ? ((Lr + 63) >> 6) : 0;
        #pragma unroll
        for (int d2 = 1; d2 < 64; d2 <<= 1) {
            a = min(a, __shfl_xor(a, d2));
            h = max(h, __shfl_xor(h, d2));
        }
        if (l == 0) { uni2[0] = a; uni2[1] = h; }
    }
    __syncthreads();
    const int alo = uni2[0], ahi = uni2[1];

    // store-wave per-iteration row params, hoisted to registers
    int Pr16[16], Lr16[16];
    if (w == 3) {
        #pragma unroll
        for (int it = 0; it < 16; ++it) {
            int row = (it << 2) + (l >> 4);
            Pr16[it] = lP[row];
            Lr16[it] = lL[row];
        }
    }

    // prologue: stage tiles alo, alo+1
    if ((w == 1 || w == 2) && alo < ahi) {
        const float* src = (w == 1) ? dur : speech;
        const int arr = w - 1;
        stage_tile(src, &lin[alo % 3][arr][0], brow, alo << 6, l);
        if (alo + 1 < ahi) {
            stage_tile(src, &lin[(alo + 1) % 3][arr][0], brow, (alo + 1) << 6, l);
            asm volatile("s_waitcnt vmcnt(16)" ::: "memory");   // tile alo landed
        } else {
            asm volatile("s_waitcnt vmcnt(0)" ::: "memory");
        }
    }
    __builtin_amdgcn_s_barrier();

    int s3 = (alo < ahi) ? (alo % 3) : 0;
    const int cg = l & 15;

    for (int t = alo; t <= ahi; ++t) {
        if (w == 0) {
            if (t < ahi) {
                // -------- chain wave: serial carry over 64 columns --------
                const int c0 = t << 6;
                const int kP = Pl - c0;
                const float* Ld = &lin[s3][0][0];
                const float* Ls = &lin[s3][1][0];
                float* LO = &lout[t & 1][0];
                float c = creg;
                #pragma unroll
                for (int g2 = 0; g2 < 16; ++g2) {
                    const int slot = (l << 4) + (g2 ^ (l & 7));
                    float4 dv = *reinterpret_cast<const float4*>(Ld + (slot << 2));
                    float4 sv = *reinterpret_cast<const float4*>(Ls + (slot << 2));
                    float fr[4];
                    float dd[4] = {dv.x, dv.y, dv.z, dv.w};
                    float sm[4] = {sv.x, sv.y, sv.z, sv.w};
                    #pragma unroll
                    for (int j = 0; j < 4; ++j) {
                        const int k = (g2 << 2) + j;
                        float m_  = rintf(sm[j]);            // (speech>0.5) as float
                        float s_  = dd[j] + c;
                        float ff_ = FRACTF(s_);
                        float t1_ = fmaxf(s_, 0.f);
                        float e_  = t1_ - m_;
                        float w_  = (s_ >= m_) ? ff_ : e_;   // carry candidate
                        bool  va_ = (unsigned)(k - kP) < kspanU;
                        c = va_ ? w_ : c;
                        fr[j] = t1_ - w_;                    // frames (raw)
                    }
                    *reinterpret_cast<float4*>(LO + (slot << 2)) =
                        make_float4(fr[0], fr[1], fr[2], fr[3]);
                }
                creg = c;
                asm volatile("s_waitcnt lgkmcnt(0)" ::: "memory"); // publish lout
            }
        } else if (w == 3) {
            if (t > alo) {
                // -------- store wave: sweep tile t-1 with boundary patches --------
                const int tp = t - 1;
                const float* LO = &lout[tp & 1][0];
                #pragma unroll
                for (int it = 0; it < 16; ++it) {
                    const int row = (it << 2) + (l >> 4);
                    const int slot = (row << 4) + (cg ^ (row & 7));
                    float4 v = *reinterpret_cast<const float4*>(LO + (slot << 2));
                    const int gg = (tp << 4) + cg;
                    const int Pr = Pr16[it], Lr = Lr16[it];
                    const int u0 = gg << 2;
                    bool instore = (Pr < Lr) && (gg >= (Pr >> 2)) && (gg < ((Lr + 3) >> 2));
                    if (instore) {
                        if (u0 < Pr) {                       // partial P-boundary group
                            float4 cbv = *reinterpret_cast<const float4*>(&lcb[row][0]);
                            v.x = (u0 + 0 >= Pr) ? v.x : cbv.x;
                            v.y = (u0 + 1 >= Pr) ? v.y : cbv.y;
                            v.z = (u0 + 2 >= Pr) ? v.z : cbv.z;
                            v.w = (u0 + 3 >= Pr) ? v.w : cbv.w;
                        }
                        if (u0 + 4 > Lr) {                   // partial L-tail group
                            v.x = (u0 + 0 < Lr) ? v.x : 0.f;
                            v.y = (u0 + 1 < Lr) ? v.y : 0.f;
                            v.z = (u0 + 2 < Lr) ? v.z : 0.f;
                            v.w = (u0 + 3 < Lr) ? v.w : 0.f;
                        }
                        size_t o = (size_t)(brow + row) * UU + (size_t)u0;
                        *reinterpret_cast<float4*>(mat  + o) = v;
                        *reinterpret_cast<float4*>(proj + o) = v;
                        *reinterpret_cast<float4*>(cach + o) = v;
                    }
                }
                asm volatile("s_waitcnt lgkmcnt(0)" ::: "memory");
            }
        } else {
            // -------- stage waves: prefetch tile t+2, counted wait --------
            if (t + 2 < ahi) {
                const int s3p2 = (s3 == 0) ? 2 : (s3 - 1);
                const float* src = (w == 1) ? dur : speech;
                stage_tile(src, &lin[s3p2][w - 1][0], brow, (t + 2) << 6, l);
            }
            if (t + 1 < ahi) {
                if (t + 2 < ahi) asm volatile("s_waitcnt vmcnt(16)" ::: "memory");
                else             asm volatile("s_waitcnt vmcnt(0)"  ::: "memory");
            }
        }
        __builtin_amdgcn_s_barrier();
        s3 = (s3 == 2) ? 0 : (s3 + 1);
    }

    if (w == 0) {
        int b = brow + l;
        resid[b] = creg;
        comm[b]  = (float)Lr_;
    }
}

extern "C" void kernel_launch(void* const* d_in, const int* in_sizes, int n_in,
                              void* d_out, int out_size, void* d_ws, size_t ws_size,
                              hipStream_t stream) {
    const float* dur            = (const float*)d_in[0];
    const float* speech         = (const float*)d_in[1];
    const float* residual_prev  = (const float*)d_in[2];
    const float* cached_prev    = (const float*)d_in[3];
    const int*   unit_len       = (const int*)d_in[4];
    const int*   sealed_len     = (const int*)d_in[5];
    const int*   committed_prev = (const int*)d_in[6];

    fused_kernel<<<NSCAN + BB, 256, 0, stream>>>(dur, speech, residual_prev, cached_prev,
                                                 unit_len, sealed_len, committed_prev,
                                                 (float*)d_out);
}

// Round 6
// 151.780 us; speedup vs baseline: 8.7745x; 1.0337x over previous
//
#include <hip/hip_runtime.h>

#define BB 2048
#define UU 4096
#define TC 64
#define NSCAN 32

typedef __attribute__((address_space(3))) void lds_void;
typedef __attribute__((address_space(1))) const void gbl_void;

__device__ __forceinline__ void gl_lds16(const float* g, float* l) {
    // async global->LDS DMA: dest = uniform base + lane*16, source per-lane
    __builtin_amdgcn_global_load_lds((gbl_void*)g, (lds_void*)l, 16, 0, 0);
}

#if __has_builtin(__builtin_amdgcn_fractf)
#define FRACTF(x) __builtin_amdgcn_fractf(x)
#else
#define FRACTF(x) ((x) - floorf(x))
#endif

// stage one 64x64 tile into swizzled LDS: slot = row*16 + (g ^ (row&7)),
// achieved by pre-swizzling the GLOBAL source (gl_lds dest is linear).
__device__ __forceinline__ void stage_tile(const float* __restrict__ src,
                                           float* dstbase, int brow, int c0, int l) {
    #pragma unroll
    for (int it = 0; it < 16; ++it) {
        int row = (it << 2) + (l >> 4);
        int gsw = (l & 15) ^ (row & 7);
        const float* g = src + (size_t)(brow + row) * UU + (size_t)(c0 + (gsw << 2));
        gl_lds16(g, dstbase + it * 256);
    }
}

__global__ __launch_bounds__(256, 1) void fused_kernel(
    const float* __restrict__ dur,
    const float* __restrict__ speech,
    const float* __restrict__ residual_prev,
    const float* __restrict__ cached_prev,
    const int* __restrict__ unit_len,
    const int* __restrict__ sealed_len,
    const int* __restrict__ committed_prev,
    float* __restrict__ out)
{
    float* mat   = out;
    float* proj  = out + (size_t)BB * UU;
    float* resid = out + 2 * (size_t)BB * UU;
    float* cach  = resid + BB;
    float* comm  = cach + (size_t)BB * UU;

    const int tid = (int)threadIdx.x;

    if (blockIdx.x >= NSCAN) {
        // ---------------- elementwise path: one row per block ----------------
        int r = (int)blockIdx.x - NSCAN;
        int L = min(unit_len[r], sealed_len[r]); L = max(0, min(L, UU));
        int P = committed_prev[r];               P = max(0, min(P, UU));
        int gs = P >> 2, ge = (L + 3) >> 2;
        bool own = P < L;
        size_t base = (size_t)r * UU;
        #pragma unroll
        for (int k2 = 0; k2 < 4; ++k2) {
            int g = (k2 << 8) + tid;                 // group index, coalesced
            if (own && g >= gs && g < ge) continue;  // scan path owns these
            int u0 = g << 2;
            float4 pv = make_float4(0.f, 0.f, 0.f, 0.f);
            if (u0 < P) pv = *reinterpret_cast<const float4*>(cached_prev + base + u0);
            float4 p4, m4;
            p4.x = (u0 + 0 < P) ? pv.x : 0.f;
            p4.y = (u0 + 1 < P) ? pv.y : 0.f;
            p4.z = (u0 + 2 < P) ? pv.z : 0.f;
            p4.w = (u0 + 3 < P) ? pv.w : 0.f;
            m4.x = (u0 + 0 < L) ? p4.x : 0.f;
            m4.y = (u0 + 1 < L) ? p4.y : 0.f;
            m4.z = (u0 + 2 < L) ? p4.z : 0.f;
            m4.w = (u0 + 3 < L) ? p4.w : 0.f;
            *reinterpret_cast<float4*>(mat  + base + u0) = m4;
            *reinterpret_cast<float4*>(proj + base + u0) = p4;
            *reinterpret_cast<float4*>(cach + base + u0) = m4;
        }
        return;
    }

    // ---------------- scan path: 4 waves, producer/consumer ----------------
    __shared__ __align__(16) float lin[3][2][64 * TC];   // 96 KB staging ring
    __shared__ __align__(16) float lout[2][64 * TC];     // 32 KB result ring
    __shared__ __align__(16) float lcb[64][4];
    __shared__ int lP[64], lL[64];
    __shared__ int uni2[2];

    const int w = tid >> 6;
    const int l = tid & 63;
    const int brow = (int)blockIdx.x << 6;

    float creg = 0.f;
    int Pl = 0, Lr_ = 0;
    unsigned kspanU = 0;

    if (w == 0) {
        int b = brow + l;
        int Lr = min(unit_len[b], sealed_len[b]); Lr = max(0, min(Lr, UU));
        int Pr = committed_prev[b];               Pr = max(0, min(Pr, UU));
        creg = residual_prev[b];
        lP[l] = Pr; lL[l] = Lr;
        Pl = Pr; Lr_ = Lr;
        bool own = Pr < Lr;
        kspanU = own ? (unsigned)(Lr - Pr) : 0u;
        float4 cbv = make_float4(0.f, 0.f, 0.f, 0.f);
        if (own && (Pr & 3))
            cbv = *reinterpret_cast<const float4*>(cached_prev + (size_t)b * UU + (size_t)(Pr & ~3));
        *reinterpret_cast<float4*>(&lcb[l][0]) = cbv;
        int a = own ? (Pr >> 6) : 0x7fffffff;
        int h = own ? ((Lr + 63) >> 6) : 0;
        #pragma unroll
        for (int d2 = 1; d2 < 64; d2 <<= 1) {
            a = min(a, __shfl_xor(a, d2));
            h = max(h, __shfl_xor(h, d2));
        }
        if (l == 0) { uni2[0] = a; uni2[1] = h; }
    }
    __syncthreads();
    const int alo = uni2[0], ahi = uni2[1];

    // store-wave per-iteration row params, hoisted to registers
    int Pr16[16], Lr16[16];
    if (w == 3) {
        #pragma unroll
        for (int it = 0; it < 16; ++it) {
            int row = (it << 2) + (l >> 4);
            Pr16[it] = lP[row];
            Lr16[it] = lL[row];
        }
    }

    // prologue: stage tiles alo, alo+1
    if ((w == 1 || w == 2) && alo < ahi) {
        const float* src = (w == 1) ? dur : speech;
        const int arr = w - 1;
        stage_tile(src, &lin[alo % 3][arr][0], brow, alo << 6, l);
        if (alo + 1 < ahi) {
            stage_tile(src, &lin[(alo + 1) % 3][arr][0], brow, (alo + 1) << 6, l);
            asm volatile("s_waitcnt vmcnt(16)" ::: "memory");   // tile alo landed
        } else {
            asm volatile("s_waitcnt vmcnt(0)" ::: "memory");
        }
    }
    __builtin_amdgcn_s_barrier();

    int s3 = (alo < ahi) ? (alo % 3) : 0;
    const int cg = l & 15;

    for (int t = alo; t <= ahi; ++t) {
        if (w == 0) {
            if (t < ahi) {
                // -------- chain wave: whole tile to registers, then serial chain --------
                const int c0 = t << 6;
                const int kP = Pl - c0;
                const float* Ld = &lin[s3][0][0];
                const float* Ls = &lin[s3][1][0];
                float* LO = &lout[t & 1][0];

                float4 DV[16], SV[16];
                #pragma unroll
                for (int g2 = 0; g2 < 16; ++g2) {
                    const int slot = (l << 4) + (g2 ^ (l & 7));
                    DV[g2] = *reinterpret_cast<const float4*>(Ld + (slot << 2));
                    SV[g2] = *reinterpret_cast<const float4*>(Ls + (slot << 2));
                }

                float c = creg;
                #pragma unroll
                for (int g2 = 0; g2 < 16; ++g2) {
                    const int slot = (l << 4) + (g2 ^ (l & 7));
                    float dd[4] = {DV[g2].x, DV[g2].y, DV[g2].z, DV[g2].w};
                    float sm[4] = {SV[g2].x, SV[g2].y, SV[g2].z, SV[g2].w};
                    float fr[4];
                    #pragma unroll
                    for (int j = 0; j < 4; ++j) {
                        const int k = (g2 << 2) + j;
                        float m_  = rintf(sm[j]);            // (speech>0.5) as float
                        float s_  = dd[j] + c;
                        float ff_ = FRACTF(s_);
                        float t1_ = fmaxf(s_, 0.f);
                        float e_  = t1_ - m_;
                        float w_  = (s_ >= m_) ? ff_ : e_;   // carry candidate
                        bool  va_ = (unsigned)(k - kP) < kspanU;
                        c = va_ ? w_ : c;
                        fr[j] = t1_ - w_;                    // frames (raw)
                    }
                    *reinterpret_cast<float4*>(LO + (slot << 2)) =
                        make_float4(fr[0], fr[1], fr[2], fr[3]);
                }
                creg = c;
                asm volatile("s_waitcnt lgkmcnt(0)" ::: "memory"); // publish lout
            }
        } else if (w == 3) {
            if (t > alo) {
                // -------- store wave: sweep tile t-1 with boundary patches --------
                const int tp = t - 1;
                const float* LO = &lout[tp & 1][0];
                #pragma unroll
                for (int it = 0; it < 16; ++it) {
                    const int row = (it << 2) + (l >> 4);
                    const int slot = (row << 4) + (cg ^ (row & 7));
                    float4 v = *reinterpret_cast<const float4*>(LO + (slot << 2));
                    const int gg = (tp << 4) + cg;
                    const int Pr = Pr16[it], Lr = Lr16[it];
                    const int u0 = gg << 2;
                    bool instore = (Pr < Lr) && (gg >= (Pr >> 2)) && (gg < ((Lr + 3) >> 2));
                    if (instore) {
                        if (u0 < Pr) {                       // partial P-boundary group
                            float4 cbv = *reinterpret_cast<const float4*>(&lcb[row][0]);
                            v.x = (u0 + 0 >= Pr) ? v.x : cbv.x;
                            v.y = (u0 + 1 >= Pr) ? v.y : cbv.y;
                            v.z = (u0 + 2 >= Pr) ? v.z : cbv.z;
                            v.w = (u0 + 3 >= Pr) ? v.w : cbv.w;
                        }
                        if (u0 + 4 > Lr) {                   // partial L-tail group
                            v.x = (u0 + 0 < Lr) ? v.x : 0.f;
                            v.y = (u0 + 1 < Lr) ? v.y : 0.f;
                            v.z = (u0 + 2 < Lr) ? v.z : 0.f;
                            v.w = (u0 + 3 < Lr) ? v.w : 0.f;
                        }
                        size_t o = (size_t)(brow + row) * UU + (size_t)u0;
                        *reinterpret_cast<float4*>(mat  + o) = v;
                        *reinterpret_cast<float4*>(proj + o) = v;
                        *reinterpret_cast<float4*>(cach + o) = v;
                    }
                }
                asm volatile("s_waitcnt lgkmcnt(0)" ::: "memory");
            }
        } else {
            // -------- stage waves: prefetch tile t+2, counted wait --------
            if (t + 2 < ahi) {
                const int s3p2 = (s3 == 0) ? 2 : (s3 - 1);
                const float* src = (w == 1) ? dur : speech;
                stage_tile(src, &lin[s3p2][w - 1][0], brow, (t + 2) << 6, l);
            }
            if (t + 1 < ahi) {
                if (t + 2 < ahi) asm volatile("s_waitcnt vmcnt(16)" ::: "memory");
                else             asm volatile("s_waitcnt vmcnt(0)"  ::: "memory");
            }
        }
        __builtin_amdgcn_s_barrier();
        s3 = (s3 == 2) ? 0 : (s3 + 1);
    }

    if (w == 0) {
        int b = brow + l;
        resid[b] = creg;
        comm[b]  = (float)Lr_;
    }
}

extern "C" void kernel_launch(void* const* d_in, const int* in_sizes, int n_in,
                              void* d_out, int out_size, void* d_ws, size_t ws_size,
                              hipStream_t stream) {
    const float* dur            = (const float*)d_in[0];
    const float* speech         = (const float*)d_in[1];
    const float* residual_prev  = (const float*)d_in[2];
    const float* cached_prev    = (const float*)d_in[3];
    const int*   unit_len       = (const int*)d_in[4];
    const int*   sealed_len     = (const int*)d_in[5];
    const int*   committed_prev = (const int*)d_in[6];

    fused_kernel<<<NSCAN + BB, 256, 0, stream>>>(dur, speech, residual_prev, cached_prev,
                                                 unit_len, sealed_len, committed_prev,
                                                 (float*)d_out);
}

// Round 7
// 129.018 us; speedup vs baseline: 10.3226x; 1.1764x over previous
//
#include <hip/hip_runtime.h>

#define BB 2048
#define UU 4096
#define TC 64
#define NSCAN 32

typedef __attribute__((address_space(3))) void lds_void;
typedef __attribute__((address_space(1))) const void gbl_void;

__device__ __forceinline__ void gl_lds16(const float* g, float* l) {
    // async global->LDS DMA: dest = uniform base + lane*16, source per-lane
    __builtin_amdgcn_global_load_lds((gbl_void*)g, (lds_void*)l, 16, 0, 0);
}

// stage one 64x64 tile into swizzled LDS: slot = row*16 + (g ^ (row&7)),
// achieved by pre-swizzling the GLOBAL source (gl_lds dest is linear).
__device__ __forceinline__ void stage_tile(const float* __restrict__ src,
                                           float* dstbase, int brow, int c0, int l) {
    #pragma unroll
    for (int it = 0; it < 16; ++it) {
        int row = (it << 2) + (l >> 4);
        int gsw = (l & 15) ^ (row & 7);
        const float* g = src + (size_t)(brow + row) * UU + (size_t)(c0 + (gsw << 2));
        gl_lds16(g, dstbase + it * 256);
    }
}

__device__ __forceinline__ void poll_ge(volatile int* f, int t) {
    while (*f < t) { }
    asm volatile("" ::: "memory");   // keep dependent LDS reads below the poll
}

__global__ __launch_bounds__(256, 1) void fused_kernel(
    const float* __restrict__ dur,
    const float* __restrict__ speech,
    const float* __restrict__ residual_prev,
    const float* __restrict__ cached_prev,
    const int* __restrict__ unit_len,
    const int* __restrict__ sealed_len,
    const int* __restrict__ committed_prev,
    float* __restrict__ out)
{
    float* mat   = out;
    float* proj  = out + (size_t)BB * UU;
    float* resid = out + 2 * (size_t)BB * UU;
    float* cach  = resid + BB;
    float* comm  = cach + (size_t)BB * UU;

    const int tid = (int)threadIdx.x;

    if (blockIdx.x >= NSCAN) {
        // ---------------- elementwise path: one row per block ----------------
        int r = (int)blockIdx.x - NSCAN;
        int L = min(unit_len[r], sealed_len[r]); L = max(0, min(L, UU));
        int P = committed_prev[r];               P = max(0, min(P, UU));
        int gs = P >> 2, ge = (L + 3) >> 2;
        bool own = P < L;
        size_t base = (size_t)r * UU;
        #pragma unroll
        for (int k2 = 0; k2 < 4; ++k2) {
            int g = (k2 << 8) + tid;                 // group index, coalesced
            if (own && g >= gs && g < ge) continue;  // scan path owns these
            int u0 = g << 2;
            float4 pv = make_float4(0.f, 0.f, 0.f, 0.f);
            if (u0 < P) pv = *reinterpret_cast<const float4*>(cached_prev + base + u0);
            float4 p4, m4;
            p4.x = (u0 + 0 < P) ? pv.x : 0.f;
            p4.y = (u0 + 1 < P) ? pv.y : 0.f;
            p4.z = (u0 + 2 < P) ? pv.z : 0.f;
            p4.w = (u0 + 3 < P) ? pv.w : 0.f;
            m4.x = (u0 + 0 < L) ? p4.x : 0.f;
            m4.y = (u0 + 1 < L) ? p4.y : 0.f;
            m4.z = (u0 + 2 < L) ? p4.z : 0.f;
            m4.w = (u0 + 3 < L) ? p4.w : 0.f;
            *reinterpret_cast<float4*>(mat  + base + u0) = m4;
            *reinterpret_cast<float4*>(proj + base + u0) = p4;
            *reinterpret_cast<float4*>(cach + base + u0) = m4;
        }
        return;
    }

    // -------- scan path: 4 waves, async SPSC pipeline (no barriers) --------
    __shared__ __align__(16) float lin[3][2][64 * TC];   // 96 KB staging ring
    __shared__ __align__(16) float lout[2][64 * TC];     // 32 KB result ring
    __shared__ __align__(16) float lcb[64][4];
    __shared__ int lP[64], lL[64];
    __shared__ int uni2[2];
    __shared__ volatile int flg[4];   // 0: dur staged, 1: speech staged,
                                      // 2: chain done, 3: lout consumed

    const int w = tid >> 6;
    const int l = tid & 63;
    const int brow = (int)blockIdx.x << 6;

    float creg = 0.f;
    int Pl = 0, Lr_ = 0;
    unsigned kspanU = 0;

    if (w == 0) {
        int b = brow + l;
        int Lr = min(unit_len[b], sealed_len[b]); Lr = max(0, min(Lr, UU));
        int Pr = committed_prev[b];               Pr = max(0, min(Pr, UU));
        creg = residual_prev[b];
        lP[l] = Pr; lL[l] = Lr;
        Pl = Pr; Lr_ = Lr;
        bool own = Pr < Lr;
        kspanU = own ? (unsigned)(Lr - Pr) : 0u;
        float4 cbv = make_float4(0.f, 0.f, 0.f, 0.f);
        if (own && (Pr & 3))
            cbv = *reinterpret_cast<const float4*>(cached_prev + (size_t)b * UU + (size_t)(Pr & ~3));
        *reinterpret_cast<float4*>(&lcb[l][0]) = cbv;
        int a = own ? (Pr >> 6) : 0x7fffffff;
        int h = own ? ((Lr + 63) >> 6) : 0;
        #pragma unroll
        for (int d2 = 1; d2 < 64; d2 <<= 1) {
            a = min(a, __shfl_xor(a, d2));
            h = max(h, __shfl_xor(h, d2));
        }
        if (l == 0) {
            uni2[0] = a; uni2[1] = h;
            flg[0] = a - 1; flg[1] = a - 1; flg[2] = a - 1; flg[3] = a - 1;
        }
    }
    __syncthreads();
    const int alo = uni2[0], ahi = uni2[1];

    if (w == 0) {
        // ---------------- chain wave ----------------
        __builtin_amdgcn_s_setprio(1);
        for (int t = alo; t < ahi; ++t) {
            poll_ge(&flg[0], t);       // dur tile staged
            poll_ge(&flg[1], t);       // speech tile staged
            poll_ge(&flg[3], t - 2);   // lout[t&1] free
            const int s3 = t % 3;
            const float* Ld = &lin[s3][0][0];
            const float* Ls = &lin[s3][1][0];
            float* LO = &lout[t & 1][0];
            const int c0 = t << 6;
            const int kP = Pl - c0;
            float c = creg;
            #pragma unroll
            for (int g2 = 0; g2 < 16; ++g2) {
                const int slot = (l << 4) + (g2 ^ (l & 7));
                float4 dv = *reinterpret_cast<const float4*>(Ld + (slot << 2));
                float4 sv = *reinterpret_cast<const float4*>(Ls + (slot << 2));
                float dd[4] = {dv.x, dv.y, dv.z, dv.w};
                float sm[4] = {sv.x, sv.y, sv.z, sv.w};
                float fr[4];
                #pragma unroll
                for (int j = 0; j < 4; ++j) {
                    const int k = (g2 << 2) + j;
                    float m_ = rintf(sm[j]);                 // (speech>0.5)
                    float s_ = dd[j] + c;
                    float f_ = fmaxf(floorf(s_), m_);        // frames
                    float cc = fmaxf(s_, 0.f) - f_;          // carry candidate
                    bool  va = (unsigned)(k - kP) < kspanU;
                    c = va ? cc : c;
                    fr[j] = f_;
                }
                *reinterpret_cast<float4*>(LO + (slot << 2)) =
                    make_float4(fr[0], fr[1], fr[2], fr[3]);
            }
            creg = c;
            asm volatile("s_waitcnt lgkmcnt(0)" ::: "memory");  // lout visible
            flg[2] = t;
        }
        __builtin_amdgcn_s_setprio(0);
        int b = brow + l;
        resid[b] = creg;
        comm[b]  = (float)Lr_;
    } else if (w == 3) {
        // ---------------- store wave ----------------
        const int cg = l & 15;
        int Pr16[16], Lr16[16];
        #pragma unroll
        for (int it = 0; it < 16; ++it) {
            int row = (it << 2) + (l >> 4);
            Pr16[it] = lP[row];
            Lr16[it] = lL[row];
        }
        for (int t = alo; t < ahi; ++t) {
            poll_ge(&flg[2], t);
            const float* LO = &lout[t & 1][0];
            float4 vv[16];
            #pragma unroll
            for (int it = 0; it < 16; ++it) {
                const int row = (it << 2) + (l >> 4);
                const int slot = (row << 4) + (cg ^ (row & 7));
                vv[it] = *reinterpret_cast<const float4*>(LO + (slot << 2));
            }
            asm volatile("s_waitcnt lgkmcnt(0)" ::: "memory");  // reads retired
            flg[3] = t;                                         // free lout early
            #pragma unroll
            for (int it = 0; it < 16; ++it) {
                const int row = (it << 2) + (l >> 4);
                float4 v = vv[it];
                const int gg = (t << 4) + cg;
                const int Pr = Pr16[it], Lr = Lr16[it];
                const int u0 = gg << 2;
                bool instore = (Pr < Lr) && (gg >= (Pr >> 2)) && (gg < ((Lr + 3) >> 2));
                if (instore) {
                    if (u0 < Pr) {                     // partial P-boundary group
                        float4 cbv = *reinterpret_cast<const float4*>(&lcb[row][0]);
                        v.x = (u0 + 0 >= Pr) ? v.x : cbv.x;
                        v.y = (u0 + 1 >= Pr) ? v.y : cbv.y;
                        v.z = (u0 + 2 >= Pr) ? v.z : cbv.z;
                        v.w = (u0 + 3 >= Pr) ? v.w : cbv.w;
                    }
                    if (u0 + 4 > Lr) {                 // partial L-tail group
                        v.x = (u0 + 0 < Lr) ? v.x : 0.f;
                        v.y = (u0 + 1 < Lr) ? v.y : 0.f;
                        v.z = (u0 + 2 < Lr) ? v.z : 0.f;
                        v.w = (u0 + 3 < Lr) ? v.w : 0.f;
                    }
                    size_t o = (size_t)(brow + row) * UU + (size_t)u0;
                    *reinterpret_cast<float4*>(mat  + o) = v;
                    *reinterpret_cast<float4*>(proj + o) = v;
                    *reinterpret_cast<float4*>(cach + o) = v;
                }
            }
        }
    } else {
        // ---------------- stage waves (w==1: dur, w==2: speech) ----------------
        const float* src = (w == 1) ? dur : speech;
        volatile int* myf = &flg[w - 1];
        const int arr = w - 1;
        for (int q = alo; q < ahi; ++q) {
            poll_ge(&flg[2], q - 3);                 // lin slot q%3 free
            stage_tile(src, &lin[q % 3][arr][0], brow, q << 6, l);
            // in-order vm retirement: <=16 outstanding => tile q-1 landed
            asm volatile("s_waitcnt vmcnt(16)" ::: "memory");
            *myf = q - 1;
        }
        if (alo < ahi) {
            asm volatile("s_waitcnt vmcnt(0)" ::: "memory");
            *myf = ahi - 1;
        }
    }
}

extern "C" void kernel_launch(void* const* d_in, const int* in_sizes, int n_in,
                              void* d_out, int out_size, void* d_ws, size_t ws_size,
                              hipStream_t stream) {
    const float* dur            = (const float*)d_in[0];
    const float* speech         = (const float*)d_in[1];
    const float* residual_prev  = (const float*)d_in[2];
    const float* cached_prev    = (const float*)d_in[3];
    const int*   unit_len       = (const int*)d_in[4];
    const int*   sealed_len     = (const int*)d_in[5];
    const int*   committed_prev = (const int*)d_in[6];

    fused_kernel<<<NSCAN + BB, 256, 0, stream>>>(dur, speech, residual_prev, cached_prev,
                                                 unit_len, sealed_len, committed_prev,
                                                 (float*)d_out);
}